// Round 1
// baseline (23266.803 us; speedup 1.0000x reference)
//
#include <hip/hip_runtime.h>
#include <math.h>

namespace {

constexpr int Bb = 1024;
constexpr int Tn = 64;
constexpr int Dn = 8;
constexpr int Hn = 64;
constexpr int Wn = 128;
constexpr int BT = 4;     // batch rows per block
constexpr int NT = 1024;  // threads per block (16 waves, 4 waves/SIMD, 1 block/CU)

// Tsit5 tableau
constexpr float A21 = 0.161f;
constexpr float A31 = -0.008480655492356989f, A32 = 0.335480655492357f;
constexpr float A41 = 2.8971530571054935f, A42 = -6.359448489975075f, A43 = 4.3622954328695815f;
constexpr float A51 = 5.325864828439257f, A52 = -11.748883564062828f, A53 = 7.4955393428898365f, A54 = -0.09249506636175525f;
constexpr float A61 = 5.86145544294642f, A62 = -12.92096931784711f, A63 = 8.159367898576159f, A64 = -0.071584973281401f, A65 = -0.028269050394068383f;
constexpr float Bc1 = 0.09646076681806523f, Bc2 = 0.01f, Bc3 = 0.4798896504144996f;
constexpr float Bc4 = 1.379008574103742f, Bc5 = -3.290069515436081f, Bc6 = 2.324710524099774f;

__device__ inline float softplus_f(float x) {
  return fmaxf(x, 0.f) + log1pf(expf(-fabsf(x)));
}
__device__ inline float dot4(float4 w, float4 a) {
  return w.x * a.x + w.y * a.y + w.z * a.z + w.w * a.w;
}

} // namespace

// Persistent per-batch-tile NeuralCDE integrator, 1024 threads/block.
//
// Register-resident vf weights now fit UNDER the compiler's 128-VGPR budget
// (the previous 512-thread version needed 176 wt-regs/thread; the allocator
// capped at 128 and spill-reloaded ~700B/thread/stage -> 39GB FETCH + 28GB
// WRITE of scratch traffic, 21.7ms). At 1024 threads each thread holds only
//   w3r[64]  : vw3 half-row   (o3 = tid>>1, half = tid&1)  -> vw3[tid*64+j]
//   w2r[16]  : vw2 1/8-row    (o  = tid>>3, g   = tid&7)   -> vw2[tid*16+j]
//   w1r[8]   : vw1 1/8-row                                  -> vw1[tid*8+j]
// = 88 weight VGPRs + ~25 workspace < 128. k-group g lives in lane bits 0-2
// so L1/L2 partial reduction is 3 shfl_xors (no LDS round-trip); L3 half in
// lane bit 0, d in bits 1-3 (shfl_xor 1 joins halves, 2/4/8 does the einsum
// reduction over d).
__attribute__((amdgpu_waves_per_eu(4, 4)))
__global__ __launch_bounds__(NT)
void ncde_kernel(const float* __restrict__ xs,
                 const float* __restrict__ iw1, const float* __restrict__ ib1,
                 const float* __restrict__ iw2, const float* __restrict__ ib2,
                 const float* __restrict__ iw3, const float* __restrict__ ib3,
                 const float* __restrict__ vw1, const float* __restrict__ vb1,
                 const float* __restrict__ vw2, const float* __restrict__ vb2,
                 const float* __restrict__ vw3, const float* __restrict__ vb3,
                 const float* __restrict__ lw,  const float* __restrict__ lb,
                 float* __restrict__ out)
{
  __shared__ float xs_l[BT][Tn * Dn];     // 8 KB control path
  __shared__ float y_l[BT][Hn];           // current state
  __shared__ float ys_l[BT][Hn];          // stage input
  __shared__ float K_l[6][BT][Hn];        // dt-scaled stage slopes
  __shared__ float h1_l[BT][Wn];
  __shared__ float h2_l[BT][Wn];
  __shared__ float dxs_l[BT][Dn];         // xs[t+1]-xs[t] (== dt * dX/dt)
  __shared__ float lw_l[Hn];

  const int tid  = threadIdx.x;
  const int g    = tid & 7;        // L1/L2 k-group (lane bits 0-2)
  const int o    = tid >> 3;       // L1/L2 output neuron, 0..127
  const int half = tid & 1;        // L3 k-half (lane bit 0)
  const int d3   = (tid >> 1) & 7; // L3 data-dim (lane bits 1-3)
  const int h3   = tid >> 4;       // L3 hidden index, 0..63
  const int b0   = blockIdx.x * BT;

  // ---- weights -> registers (perfectly linear, coalesced, one-time) ----
  float w1r[8];
  {
    const float4* p = (const float4*)(vw1 + tid * 8);
    #pragma unroll
    for (int i = 0; i < 2; ++i) {
      float4 v = p[i];
      w1r[i*4+0] = v.x; w1r[i*4+1] = v.y; w1r[i*4+2] = v.z; w1r[i*4+3] = v.w;
    }
  }
  float w2r[16];
  {
    const float4* p = (const float4*)(vw2 + tid * 16);
    #pragma unroll
    for (int i = 0; i < 4; ++i) {
      float4 v = p[i];
      w2r[i*4+0] = v.x; w2r[i*4+1] = v.y; w2r[i*4+2] = v.z; w2r[i*4+3] = v.w;
    }
  }
  float w3r[64];
  {
    const float4* p = (const float4*)(vw3 + tid * 64);
    #pragma unroll
    for (int i = 0; i < 16; ++i) {
      float4 v = p[i];
      w3r[i*4+0] = v.x; w3r[i*4+1] = v.y; w3r[i*4+2] = v.z; w3r[i*4+3] = v.w;
    }
  }
  const float b1r = vb1[o];
  const float b2r = vb2[o];
  const float b3r = vb3[tid >> 1];
  const float lb0 = lb[0];

  // ---- stage this block's xs rows (512 x float4 = 8 KB) ----
  if (tid < 512)
    ((float4*)&xs_l[0][0])[tid] = ((const float4*)(xs + b0 * Tn * Dn))[tid];
  if (tid < Hn) lw_l[tid] = lw[tid];
  __syncthreads();

  // ---- initial MLP (relu, relu, identity): y0 = mlp(xs[:,0]) ----
  if (tid < 512) {
    const int b = tid >> 7, oo = tid & 127;
    float acc = ib1[oo];
    #pragma unroll
    for (int k = 0; k < Dn; ++k) acc += iw1[oo * Dn + k] * xs_l[b][k];
    h1_l[b][oo] = fmaxf(acc, 0.f);
  }
  __syncthreads();
  if (tid < 512) {
    const int b = tid >> 7, oo = tid & 127;
    float acc = ib2[oo];
    const float4* wrow = (const float4*)(iw2 + oo * Wn);
    #pragma unroll
    for (int k4 = 0; k4 < Wn / 4; ++k4)
      acc += dot4(wrow[k4], *(const float4*)&h1_l[b][k4 * 4]);
    h2_l[b][oo] = fmaxf(acc, 0.f);
  }
  __syncthreads();
  if (tid < BT * Hn) {
    const int b = tid >> 6, h = tid & (Hn - 1);
    float acc = ib3[h];
    const float4* wrow = (const float4*)(iw3 + h * Wn);
    #pragma unroll
    for (int k4 = 0; k4 < Wn / 4; ++k4)
      acc += dot4(wrow[k4], *(const float4*)&h2_l[b][k4 * 4]);
    y_l[b][h] = acc;
  }
  __syncthreads();

  auto readout = [&](int t) {
    if (tid < BT * Hn) {
      const int wv = tid >> 6, h = tid & (Hn - 1);
      float p = lw_l[h] * y_l[wv][h];
      #pragma unroll
      for (int off = 32; off > 0; off >>= 1) p += __shfl_xor(p, off, 64);
      if (h == 0) out[(b0 + wv) * Tn + t] = 1.f / (1.f + expf(-(p + lb0)));
    }
  };
  readout(0);

  // ---- 63 Tsit5 steps ----
  for (int t = 0; t < Tn - 1; ++t) {
    if (tid < BT * Hn) {
      const int b = tid >> 6, h = tid & (Hn - 1);
      ys_l[b][h] = y_l[b][h];               // stage-1 input is y
    } else if (tid < BT * Hn + BT * Dn) {
      const int r = tid - BT * Hn;
      const int b = r >> 3, dd = r & 7;
      dxs_l[b][dd] = xs_l[b][(t + 1) * Dn + dd] - xs_l[b][t * Dn + dd];
    }
    __syncthreads();

    float dxr[BT];
    #pragma unroll
    for (int b = 0; b < BT; ++b) dxr[b] = dxs_l[b][d3];

    #pragma unroll
    for (int s = 0; s < 6; ++s) {
      // ---- vf layer 1: [4,64] -> [4,128], k split 8 ways across lane bits ----
      {
        float a[BT] = {0.f, 0.f, 0.f, 0.f};
        #pragma unroll
        for (int j4 = 0; j4 < 2; ++j4) {
          #pragma unroll
          for (int b = 0; b < BT; ++b) {
            const float4 av = *(const float4*)&ys_l[b][g * 8 + j4 * 4];
            a[b] += w1r[j4*4+0] * av.x + w1r[j4*4+1] * av.y
                  + w1r[j4*4+2] * av.z + w1r[j4*4+3] * av.w;
          }
        }
        float hv = 0.f;
        #pragma unroll
        for (int b = 0; b < BT; ++b) {
          float r = a[b];
          r += __shfl_xor(r, 1, 64);
          r += __shfl_xor(r, 2, 64);
          r += __shfl_xor(r, 4, 64);
          if (g == b) hv = r;       // lane g holds batch-row g's sum
        }
        if (g < BT) h1_l[g][o] = softplus_f(hv + b1r);
      }
      __syncthreads();
      // ---- vf layer 2: [4,128] -> [4,128], k split 8 ways ----
      {
        float a[BT] = {0.f, 0.f, 0.f, 0.f};
        #pragma unroll
        for (int j4 = 0; j4 < 4; ++j4) {
          #pragma unroll
          for (int b = 0; b < BT; ++b) {
            const float4 av = *(const float4*)&h1_l[b][g * 16 + j4 * 4];
            a[b] += w2r[j4*4+0] * av.x + w2r[j4*4+1] * av.y
                  + w2r[j4*4+2] * av.z + w2r[j4*4+3] * av.w;
          }
        }
        float hv = 0.f;
        #pragma unroll
        for (int b = 0; b < BT; ++b) {
          float r = a[b];
          r += __shfl_xor(r, 1, 64);
          r += __shfl_xor(r, 2, 64);
          r += __shfl_xor(r, 4, 64);
          if (g == b) hv = r;
        }
        if (g < BT) h2_l[g][o] = softplus_f(hv + b2r);
      }
      __syncthreads();
      // ---- vf layer 3: [4,128] -> [4,512], k split 2 ways, tanh, einsum ----
      {
        float a[BT] = {0.f, 0.f, 0.f, 0.f};
        #pragma unroll
        for (int k4 = 0; k4 < 16; ++k4) {
          #pragma unroll
          for (int b = 0; b < BT; ++b) {
            const float4 av = *(const float4*)&h2_l[b][half * 64 + k4 * 4];
            a[b] += w3r[k4*4+0] * av.x + w3r[k4*4+1] * av.y
                  + w3r[k4*4+2] * av.z + w3r[k4*4+3] * av.w;
          }
        }
        #pragma unroll
        for (int b = 0; b < BT; ++b) {
          float full = a[b] + __shfl_xor(a[b], 1, 64);   // join k-halves
          float p = tanhf(full + b3r) * dxr[b];
          p += __shfl_xor(p, 2, 64);                      // reduce over d
          p += __shfl_xor(p, 4, 64);
          p += __shfl_xor(p, 8, 64);
          if ((tid & 15) == 0) K_l[s][b][h3] = p;
        }
      }
      __syncthreads();
      // ---- stage prep / final update ----
      if (tid < BT * Hn) {
        const int b = tid >> 6, h = tid & (Hn - 1);
        float v = y_l[b][h];
        if (s == 0)      v += A21 * K_l[0][b][h];
        else if (s == 1) v += A31 * K_l[0][b][h] + A32 * K_l[1][b][h];
        else if (s == 2) v += A41 * K_l[0][b][h] + A42 * K_l[1][b][h] + A43 * K_l[2][b][h];
        else if (s == 3) v += A51 * K_l[0][b][h] + A52 * K_l[1][b][h] + A53 * K_l[2][b][h] + A54 * K_l[3][b][h];
        else if (s == 4) v += A61 * K_l[0][b][h] + A62 * K_l[1][b][h] + A63 * K_l[2][b][h] + A64 * K_l[3][b][h] + A65 * K_l[4][b][h];
        else             v += Bc1 * K_l[0][b][h] + Bc2 * K_l[1][b][h] + Bc3 * K_l[2][b][h]
                            + Bc4 * K_l[3][b][h] + Bc5 * K_l[4][b][h] + Bc6 * K_l[5][b][h];
        if (s < 5) ys_l[b][h] = v; else y_l[b][h] = v;
      }
      __syncthreads();
    }
    readout(t + 1);
  }
}

extern "C" void kernel_launch(void* const* d_in, const int* in_sizes, int n_in,
                              void* d_out, int out_size, void* d_ws, size_t ws_size,
                              hipStream_t stream) {
  const float* xs  = (const float*)d_in[1];
  const float* iw1 = (const float*)d_in[2];
  const float* ib1 = (const float*)d_in[3];
  const float* iw2 = (const float*)d_in[4];
  const float* ib2 = (const float*)d_in[5];
  const float* iw3 = (const float*)d_in[6];
  const float* ib3 = (const float*)d_in[7];
  const float* vw1 = (const float*)d_in[8];
  const float* vb1 = (const float*)d_in[9];
  const float* vw2 = (const float*)d_in[10];
  const float* vb2 = (const float*)d_in[11];
  const float* vw3 = (const float*)d_in[12];
  const float* vb3 = (const float*)d_in[13];
  const float* lw  = (const float*)d_in[14];
  const float* lb  = (const float*)d_in[15];
  float* out = (float*)d_out;

  ncde_kernel<<<Bb / BT, NT, 0, stream>>>(xs, iw1, ib1, iw2, ib2, iw3, ib3,
                                          vw1, vb1, vw2, vb2, vw3, vb3, lw, lb, out);
}

// Round 2
// 23186.121 us; speedup vs baseline: 1.0035x; 1.0035x over previous
//
#include <hip/hip_runtime.h>
#include <math.h>

namespace {

constexpr int Bb = 1024;
constexpr int Tn = 64;
constexpr int Dn = 8;
constexpr int Hn = 64;
constexpr int Wn = 128;
constexpr int BT = 4;    // batch rows per block
constexpr int NT = 512;  // threads per block (8 waves, 2 waves/SIMD, 1 block/CU)

// Tsit5 tableau
constexpr float A21 = 0.161f;
constexpr float A31 = -0.008480655492356989f, A32 = 0.335480655492357f;
constexpr float A41 = 2.8971530571054935f, A42 = -6.359448489975075f, A43 = 4.3622954328695815f;
constexpr float A51 = 5.325864828439257f, A52 = -11.748883564062828f, A53 = 7.4955393428898365f, A54 = -0.09249506636175525f;
constexpr float A61 = 5.86145544294642f, A62 = -12.92096931784711f, A63 = 8.159367898576159f, A64 = -0.071584973281401f, A65 = -0.028269050394068383f;
constexpr float Bc1 = 0.09646076681806523f, Bc2 = 0.01f, Bc3 = 0.4798896504144996f;
constexpr float Bc4 = 1.379008574103742f, Bc5 = -3.290069515436081f, Bc6 = 2.324710524099774f;

__device__ inline float softplus_f(float x) {
  return fmaxf(x, 0.f) + log1pf(expf(-fabsf(x)));
}
__device__ inline float dot4(float4 w, float4 a) {
  return w.x * a.x + w.y * a.y + w.z * a.z + w.w * a.w;
}

} // namespace

// Persistent per-batch-tile NeuralCDE integrator, 512 threads/block.
//
// KEY CHANGE vs previous rounds: stop fighting the register allocator.
// Both prior attempts spilled because the occupancy heuristic targeted
// 2 workgroups/CU and capped VGPRs (128 then 64) below the register-
// resident weight footprint -> 45-75 GB of scratch traffic per dispatch.
// Now:
//   * vw1 (32KB) + vw2 (64KB) live in LDS, TRANSPOSED (wT[k][o]): reads
//     are consecutive-o across lanes -> conflict-free broadcast.
//   * LDS total ~116KB -> only 1 block/CU fits -> compiler's own occupancy
//     bound is 2 waves/SIMD -> 256-VGPR budget by its own arithmetic.
//   * __launch_bounds__(512, 2): sanctioned min-waves/EU knob (the bare
//     amdgpu_waves_per_eu attribute was ignored in R0/R1).
//   * Only vw3 stays register-resident: thread tid holds row tid
//     (w3r[128] = 128 VGPRs), + ~40 workspace ~= 170 < 256.
// L1/L2 k-split in lane bits 0-1 (2 shfl_xors, no LDS round-trip);
// L3 reduce over d in lane bits 0-2 (3 shfl_xors). tanh computed exactly
// once per (row, batch). s-loop kept rolled to stay inside L1I.
__global__ __launch_bounds__(NT, 2)
void ncde_kernel(const float* __restrict__ xs,
                 const float* __restrict__ iw1, const float* __restrict__ ib1,
                 const float* __restrict__ iw2, const float* __restrict__ ib2,
                 const float* __restrict__ iw3, const float* __restrict__ ib3,
                 const float* __restrict__ vw1, const float* __restrict__ vb1,
                 const float* __restrict__ vw2, const float* __restrict__ vb2,
                 const float* __restrict__ vw3, const float* __restrict__ vb3,
                 const float* __restrict__ lw,  const float* __restrict__ lb,
                 float* __restrict__ out)
{
  __shared__ float w1T[Hn][Wn];           // 32 KB: w1T[k][o] = vw1[o*Hn+k]
  __shared__ float w2T[Wn][Wn];           // 64 KB: w2T[k][o] = vw2[o*Wn+k]
  __shared__ float xs_l[BT][Tn * Dn];     // 8 KB control path
  __shared__ float y_l[BT][Hn];           // current state
  __shared__ float ys_l[BT][Hn];          // stage input
  __shared__ float K_l[6][BT][Hn];        // dt-scaled stage slopes
  __shared__ float h1_l[BT][Wn];
  __shared__ float h2_l[BT][Wn];
  __shared__ float dxs_l[BT][Dn];         // xs[t+1]-xs[t] (== dt * dX/dt)
  __shared__ float lw_l[Hn];

  const int tid = threadIdx.x;
  const int g2  = tid & 3;        // L1/L2 k-group (lane bits 0-1)
  const int o   = tid >> 2;       // L1/L2 output neuron, 0..127
  const int d   = tid & 7;        // L3 data-dim (lane bits 0-2)
  const int h3  = tid >> 3;       // L3 hidden index, 0..63
  const int b0  = blockIdx.x * BT;

  // ---- vw3 row tid -> registers (coalesced float4, one-time) ----
  float w3r[128];
  {
    const float4* p = (const float4*)(vw3 + tid * Wn);
    #pragma unroll
    for (int i = 0; i < 32; ++i) {
      float4 v = p[i];
      w3r[4*i+0] = v.x; w3r[4*i+1] = v.y; w3r[4*i+2] = v.z; w3r[4*i+3] = v.w;
    }
  }
  const float b1r = vb1[o];
  const float b2r = vb2[o];
  const float b3r = vb3[tid];
  const float lb0 = lb[0];

  // ---- stage w1/w2 transposed into LDS (coalesced global reads) ----
  #pragma unroll
  for (int i = 0; i < 16; ++i) {          // 8192 f32 / 512 threads
    const int e = i * NT + tid;           // e = o*64 + k
    w1T[e & 63][e >> 6] = vw1[e];
  }
  #pragma unroll
  for (int i = 0; i < 32; ++i) {          // 16384 f32 / 512 threads
    const int e = i * NT + tid;           // e = o*128 + k
    w2T[e & 127][e >> 7] = vw2[e];
  }
  // ---- this block's xs rows (512 x float4 = 8 KB) ----
  ((float4*)&xs_l[0][0])[tid] = ((const float4*)(xs + b0 * Tn * Dn))[tid];
  if (tid < Hn) lw_l[tid] = lw[tid];
  __syncthreads();

  // ---- initial MLP (relu, relu, identity): y0 = mlp(xs[:,0]) ----
  {
    const int b = tid >> 7, oo = tid & 127;
    float acc = ib1[oo];
    #pragma unroll
    for (int k = 0; k < Dn; ++k) acc += iw1[oo * Dn + k] * xs_l[b][k];
    h1_l[b][oo] = fmaxf(acc, 0.f);
  }
  __syncthreads();
  {
    const int b = tid >> 7, oo = tid & 127;
    float acc = ib2[oo];
    const float4* wrow = (const float4*)(iw2 + oo * Wn);
    #pragma unroll
    for (int k4 = 0; k4 < Wn / 4; ++k4)
      acc += dot4(wrow[k4], *(const float4*)&h1_l[b][k4 * 4]);
    h2_l[b][oo] = fmaxf(acc, 0.f);
  }
  __syncthreads();
  if (tid < BT * Hn) {
    const int b = tid >> 6, h = tid & (Hn - 1);
    float acc = ib3[h];
    const float4* wrow = (const float4*)(iw3 + h * Wn);
    #pragma unroll
    for (int k4 = 0; k4 < Wn / 4; ++k4)
      acc += dot4(wrow[k4], *(const float4*)&h2_l[b][k4 * 4]);
    y_l[b][h] = acc;
  }
  __syncthreads();

  auto readout = [&](int t) {
    if (tid < BT * Hn) {
      const int wv = tid >> 6, h = tid & (Hn - 1);
      float p = lw_l[h] * y_l[wv][h];
      #pragma unroll
      for (int off = 32; off > 0; off >>= 1) p += __shfl_xor(p, off, 64);
      if (h == 0) out[(b0 + wv) * Tn + t] = 1.f / (1.f + expf(-(p + lb0)));
    }
  };
  readout(0);

  // ---- 63 Tsit5 steps ----
  #pragma unroll 1
  for (int t = 0; t < Tn - 1; ++t) {
    if (tid < BT * Hn) {
      const int b = tid >> 6, h = tid & (Hn - 1);
      ys_l[b][h] = y_l[b][h];               // stage-1 input is y
    } else if (tid < BT * Hn + BT * Dn) {
      const int r = tid - BT * Hn;
      const int b = r >> 3, dd = r & 7;
      dxs_l[b][dd] = xs_l[b][(t + 1) * Dn + dd] - xs_l[b][t * Dn + dd];
    }
    __syncthreads();

    float dxr[BT];
    #pragma unroll
    for (int b = 0; b < BT; ++b) dxr[b] = dxs_l[b][d];

    #pragma unroll 1
    for (int s = 0; s < 6; ++s) {
      // ---- vf layer 1: [4,64] -> [4,128], k split 4 ways (interleaved chunks) ----
      {
        float a[BT] = {0.f, 0.f, 0.f, 0.f};
        #pragma unroll
        for (int jj = 0; jj < 4; ++jj) {
          const int c = g2 + 4 * jj;       // float4 chunk of k (bank-spread)
          float wv[4];
          #pragma unroll
          for (int m = 0; m < 4; ++m) wv[m] = w1T[c * 4 + m][o];
          #pragma unroll
          for (int b = 0; b < BT; ++b) {
            const float4 av = *(const float4*)&ys_l[b][c * 4];
            a[b] += wv[0] * av.x + wv[1] * av.y + wv[2] * av.z + wv[3] * av.w;
          }
        }
        float hv = 0.f;
        #pragma unroll
        for (int b = 0; b < BT; ++b) {
          float r = a[b];
          r += __shfl_xor(r, 1, 64);
          r += __shfl_xor(r, 2, 64);
          if (g2 == b) hv = r;              // lane g2 keeps batch-row g2
        }
        h1_l[g2][o] = softplus_f(hv + b1r);
      }
      __syncthreads();
      // ---- vf layer 2: [4,128] -> [4,128], k split 4 ways ----
      {
        float a[BT] = {0.f, 0.f, 0.f, 0.f};
        #pragma unroll
        for (int jj = 0; jj < 8; ++jj) {
          const int c = g2 + 4 * jj;
          float wv[4];
          #pragma unroll
          for (int m = 0; m < 4; ++m) wv[m] = w2T[c * 4 + m][o];
          #pragma unroll
          for (int b = 0; b < BT; ++b) {
            const float4 av = *(const float4*)&h1_l[b][c * 4];
            a[b] += wv[0] * av.x + wv[1] * av.y + wv[2] * av.z + wv[3] * av.w;
          }
        }
        float hv = 0.f;
        #pragma unroll
        for (int b = 0; b < BT; ++b) {
          float r = a[b];
          r += __shfl_xor(r, 1, 64);
          r += __shfl_xor(r, 2, 64);
          if (g2 == b) hv = r;
        }
        h2_l[g2][o] = softplus_f(hv + b2r);
      }
      __syncthreads();
      // ---- vf layer 3: [4,128] -> [4,512] (row tid), tanh, einsum over d ----
      {
        float a[BT] = {0.f, 0.f, 0.f, 0.f};
        #pragma unroll
        for (int k4 = 0; k4 < 32; ++k4) {
          #pragma unroll
          for (int b = 0; b < BT; ++b) {
            const float4 av = *(const float4*)&h2_l[b][k4 * 4];  // uniform: broadcast
            a[b] += w3r[4*k4+0] * av.x + w3r[4*k4+1] * av.y
                  + w3r[4*k4+2] * av.z + w3r[4*k4+3] * av.w;
          }
        }
        float kv = 0.f;
        #pragma unroll
        for (int b = 0; b < BT; ++b) {
          float p = tanhf(a[b] + b3r) * dxr[b];
          p += __shfl_xor(p, 1, 64);        // reduce over d (lane bits 0-2)
          p += __shfl_xor(p, 2, 64);
          p += __shfl_xor(p, 4, 64);
          if (d == b) kv = p;
        }
        if (d < BT) K_l[s][d][h3] = kv;
      }
      __syncthreads();
      // ---- stage prep / final update ----
      if (tid < BT * Hn) {
        const int b = tid >> 6, h = tid & (Hn - 1);
        float v = y_l[b][h];
        if (s == 0)      v += A21 * K_l[0][b][h];
        else if (s == 1) v += A31 * K_l[0][b][h] + A32 * K_l[1][b][h];
        else if (s == 2) v += A41 * K_l[0][b][h] + A42 * K_l[1][b][h] + A43 * K_l[2][b][h];
        else if (s == 3) v += A51 * K_l[0][b][h] + A52 * K_l[1][b][h] + A53 * K_l[2][b][h] + A54 * K_l[3][b][h];
        else if (s == 4) v += A61 * K_l[0][b][h] + A62 * K_l[1][b][h] + A63 * K_l[2][b][h] + A64 * K_l[3][b][h] + A65 * K_l[4][b][h];
        else             v += Bc1 * K_l[0][b][h] + Bc2 * K_l[1][b][h] + Bc3 * K_l[2][b][h]
                            + Bc4 * K_l[3][b][h] + Bc5 * K_l[4][b][h] + Bc6 * K_l[5][b][h];
        if (s < 5) ys_l[b][h] = v; else y_l[b][h] = v;
      }
      __syncthreads();
    }
    readout(t + 1);
  }
}

extern "C" void kernel_launch(void* const* d_in, const int* in_sizes, int n_in,
                              void* d_out, int out_size, void* d_ws, size_t ws_size,
                              hipStream_t stream) {
  const float* xs  = (const float*)d_in[1];
  const float* iw1 = (const float*)d_in[2];
  const float* ib1 = (const float*)d_in[3];
  const float* iw2 = (const float*)d_in[4];
  const float* ib2 = (const float*)d_in[5];
  const float* iw3 = (const float*)d_in[6];
  const float* ib3 = (const float*)d_in[7];
  const float* vw1 = (const float*)d_in[8];
  const float* vb1 = (const float*)d_in[9];
  const float* vw2 = (const float*)d_in[10];
  const float* vb2 = (const float*)d_in[11];
  const float* vw3 = (const float*)d_in[12];
  const float* vb3 = (const float*)d_in[13];
  const float* lw  = (const float*)d_in[14];
  const float* lb  = (const float*)d_in[15];
  float* out = (float*)d_out;

  ncde_kernel<<<Bb / BT, NT, 0, stream>>>(xs, iw1, ib1, iw2, ib2, iw3, ib3,
                                          vw1, vb1, vw2, vb2, vw3, vb3, lw, lb, out);
}

// Round 3
// 4209.337 us; speedup vs baseline: 5.5274x; 5.5083x over previous
//
#include <hip/hip_runtime.h>
#include <math.h>

namespace {

constexpr int Bb = 1024;
constexpr int Tn = 64;
constexpr int Dn = 8;
constexpr int Hn = 64;
constexpr int Wn = 128;
constexpr int BT = 4;    // batch rows per block
constexpr int NT = 512;  // threads per block
constexpr int WP = 132;  // padded LDS stride for weight tiles: 132 % 8 == 4
                         // -> 4 consecutive k-rows land 16 banks apart -> 2-way (free)

// Tsit5 tableau
constexpr float A21 = 0.161f;
constexpr float A31 = -0.008480655492356989f, A32 = 0.335480655492357f;
constexpr float A41 = 2.8971530571054935f, A42 = -6.359448489975075f, A43 = 4.3622954328695815f;
constexpr float A51 = 5.325864828439257f, A52 = -11.748883564062828f, A53 = 7.4955393428898365f, A54 = -0.09249506636175525f;
constexpr float A61 = 5.86145544294642f, A62 = -12.92096931784711f, A63 = 8.159367898576159f, A64 = -0.071584973281401f, A65 = -0.028269050394068383f;
constexpr float Bc1 = 0.09646076681806523f, Bc2 = 0.01f, Bc3 = 0.4798896504144996f;
constexpr float Bc4 = 1.379008574103742f, Bc5 = -3.290069515436081f, Bc6 = 2.324710524099774f;

__device__ inline float softplus_f(float x) {
  return fmaxf(x, 0.f) + log1pf(expf(-fabsf(x)));
}
__device__ inline float dot4(float4 w, float4 a) {
  return w.x * a.x + w.y * a.y + w.z * a.z + w.w * a.w;
}

} // namespace

// Persistent per-batch-tile NeuralCDE integrator, 512 threads/block.
//
// VGPR reality (R0-R2 evidence): backend always budgets 1024/waves_per_block
// VGPRs (2 workgroups/CU model), ignoring waves_per_eu and LDS occupancy.
// At 512 threads the cap is 128 -- so this version is DESIGNED to fit 128:
//   * w1T/w2T in LDS (stride-132 padded: k-row reads are 2-way/free).
//   * vw3: k=0..63 of row tid register-resident (w3r[64]); k=64..127
//     STREAMED from global each stage (128 KB, L2-hot for the whole XCD).
//     Octet-cooperative coalesced loads: lane j reads row*512+256+j*16,
//     3 shfl_xors reduce the k-partials, lane rr==d keeps row 8*h3+rr.
//   * asm-opaque base pointer per stage prevents LICM from hoisting the
//     streamed half back into registers (which would recreate the spill).
// Budget: 64 (w3r) + 32 (h2 cache) + ~28 transients < 128, zero scratch.
__global__ __attribute__((amdgpu_waves_per_eu(2, 2))) __launch_bounds__(NT)
void ncde_kernel(const float* __restrict__ xs,
                 const float* __restrict__ iw1, const float* __restrict__ ib1,
                 const float* __restrict__ iw2, const float* __restrict__ ib2,
                 const float* __restrict__ iw3, const float* __restrict__ ib3,
                 const float* __restrict__ vw1, const float* __restrict__ vb1,
                 const float* __restrict__ vw2, const float* __restrict__ vb2,
                 const float* __restrict__ vw3, const float* __restrict__ vb3,
                 const float* __restrict__ lw,  const float* __restrict__ lb,
                 float* __restrict__ out)
{
  __shared__ float w1T[Hn][WP];           // 33.8 KB: w1T[k][o] = vw1[o*Hn+k]
  __shared__ float w2T[Wn][WP];           // 67.6 KB: w2T[k][o] = vw2[o*Wn+k]
  __shared__ float xs_l[BT][Tn * Dn];     // 8 KB control path
  __shared__ float y_l[BT][Hn];           // current state
  __shared__ float ys_l[BT][Hn];          // stage input
  __shared__ float K_l[6][BT][Hn];        // dt-scaled stage slopes
  __shared__ float h1_l[BT][Wn];
  __shared__ float h2_l[BT][Wn];
  __shared__ float dxs_l[BT][Dn];         // xs[t+1]-xs[t] (== dt * dX/dt)
  __shared__ float lw_l[Hn];

  const int tid = threadIdx.x;
  const int g2  = tid & 3;        // L1/L2 k-group (lane bits 0-1)
  const int o   = tid >> 2;       // L1/L2 output neuron, 0..127
  const int d   = tid & 7;        // L3 data-dim / octet lane (bits 0-2)
  const int h3  = tid >> 3;       // L3 hidden index / octet id, 0..63
  const int b0  = blockIdx.x * BT;

  // ---- vw3 row tid, FRONT half (k=0..63) -> registers (one-time) ----
  float w3r[64];
  {
    const float4* p = (const float4*)(vw3 + tid * Wn);
    #pragma unroll
    for (int i = 0; i < 16; ++i) {
      float4 v = p[i];
      w3r[4*i+0] = v.x; w3r[4*i+1] = v.y; w3r[4*i+2] = v.z; w3r[4*i+3] = v.w;
    }
  }
  const float b1r = vb1[o];
  const float b2r = vb2[o];
  const float b3r = vb3[tid];
  const float lb0 = lb[0];

  // ---- stage w1/w2 transposed+padded into LDS ----
  #pragma unroll
  for (int i = 0; i < 16; ++i) {          // 8192 f32 / 512 threads
    const int e = i * NT + tid;           // e = o*64 + k
    w1T[e & 63][e >> 6] = vw1[e];
  }
  #pragma unroll
  for (int i = 0; i < 32; ++i) {          // 16384 f32 / 512 threads
    const int e = i * NT + tid;           // e = o*128 + k
    w2T[e & 127][e >> 7] = vw2[e];
  }
  // ---- this block's xs rows (512 x float4 = 8 KB) ----
  ((float4*)&xs_l[0][0])[tid] = ((const float4*)(xs + b0 * Tn * Dn))[tid];
  if (tid < Hn) lw_l[tid] = lw[tid];
  __syncthreads();

  // ---- initial MLP (relu, relu, identity): y0 = mlp(xs[:,0]) ----
  {
    const int b = tid >> 7, oo = tid & 127;
    float acc = ib1[oo];
    #pragma unroll
    for (int k = 0; k < Dn; ++k) acc += iw1[oo * Dn + k] * xs_l[b][k];
    h1_l[b][oo] = fmaxf(acc, 0.f);
  }
  __syncthreads();
  {
    const int b = tid >> 7, oo = tid & 127;
    float acc = ib2[oo];
    const float4* wrow = (const float4*)(iw2 + oo * Wn);
    #pragma unroll
    for (int k4 = 0; k4 < Wn / 4; ++k4)
      acc += dot4(wrow[k4], *(const float4*)&h1_l[b][k4 * 4]);
    h2_l[b][oo] = fmaxf(acc, 0.f);
  }
  __syncthreads();
  if (tid < BT * Hn) {
    const int b = tid >> 6, h = tid & (Hn - 1);
    float acc = ib3[h];
    const float4* wrow = (const float4*)(iw3 + h * Wn);
    #pragma unroll
    for (int k4 = 0; k4 < Wn / 4; ++k4)
      acc += dot4(wrow[k4], *(const float4*)&h2_l[b][k4 * 4]);
    y_l[b][h] = acc;
  }
  __syncthreads();

  auto readout = [&](int t) {
    if (tid < BT * Hn) {
      const int wv = tid >> 6, h = tid & (Hn - 1);
      float p = lw_l[h] * y_l[wv][h];
      #pragma unroll
      for (int off = 32; off > 0; off >>= 1) p += __shfl_xor(p, off, 64);
      if (h == 0) out[(b0 + wv) * Tn + t] = 1.f / (1.f + expf(-(p + lb0)));
    }
  };
  readout(0);

  // ---- 63 Tsit5 steps ----
  #pragma unroll 1
  for (int t = 0; t < Tn - 1; ++t) {
    if (tid < BT * Hn) {
      const int b = tid >> 6, h = tid & (Hn - 1);
      ys_l[b][h] = y_l[b][h];               // stage-1 input is y
    } else if (tid < BT * Hn + BT * Dn) {
      const int r = tid - BT * Hn;
      const int b = r >> 3, dd = r & 7;
      dxs_l[b][dd] = xs_l[b][(t + 1) * Dn + dd] - xs_l[b][t * Dn + dd];
    }
    __syncthreads();

    float dxr[BT];
    #pragma unroll
    for (int b = 0; b < BT; ++b) dxr[b] = dxs_l[b][d];

    #pragma unroll 1
    for (int s = 0; s < 6; ++s) {
      // ---- vf layer 1: [4,64] -> [4,128], k split 4 ways ----
      {
        float a[BT] = {0.f, 0.f, 0.f, 0.f};
        #pragma unroll
        for (int jj = 0; jj < 4; ++jj) {
          const int c = g2 + 4 * jj;       // float4 chunk of k
          float wv[4];
          #pragma unroll
          for (int m = 0; m < 4; ++m) wv[m] = w1T[c * 4 + m][o];
          #pragma unroll
          for (int b = 0; b < BT; ++b) {
            const float4 av = *(const float4*)&ys_l[b][c * 4];
            a[b] += wv[0] * av.x + wv[1] * av.y + wv[2] * av.z + wv[3] * av.w;
          }
        }
        float hv = 0.f;
        #pragma unroll
        for (int b = 0; b < BT; ++b) {
          float r = a[b];
          r += __shfl_xor(r, 1, 64);
          r += __shfl_xor(r, 2, 64);
          if (g2 == b) hv = r;              // lane g2 keeps batch-row g2
        }
        h1_l[g2][o] = softplus_f(hv + b1r);
      }
      __syncthreads();
      // ---- vf layer 2: [4,128] -> [4,128], k split 4 ways ----
      {
        float a[BT] = {0.f, 0.f, 0.f, 0.f};
        #pragma unroll
        for (int jj = 0; jj < 8; ++jj) {
          const int c = g2 + 4 * jj;
          float wv[4];
          #pragma unroll
          for (int m = 0; m < 4; ++m) wv[m] = w2T[c * 4 + m][o];
          #pragma unroll
          for (int b = 0; b < BT; ++b) {
            const float4 av = *(const float4*)&h1_l[b][c * 4];
            a[b] += wv[0] * av.x + wv[1] * av.y + wv[2] * av.z + wv[3] * av.w;
          }
        }
        float hv = 0.f;
        #pragma unroll
        for (int b = 0; b < BT; ++b) {
          float r = a[b];
          r += __shfl_xor(r, 1, 64);
          r += __shfl_xor(r, 2, 64);
          if (g2 == b) hv = r;
        }
        h2_l[g2][o] = softplus_f(hv + b2r);
      }
      __syncthreads();
      // ---- vf layer 3: row tid = h3*8+d; front half from w3r, back half
      //      streamed (octet-coalesced, L2-hot), tanh, einsum over d ----
      {
        // register half: k = 0..63
        float a3[BT] = {0.f, 0.f, 0.f, 0.f};
        #pragma unroll
        for (int k4 = 0; k4 < 16; ++k4) {
          #pragma unroll
          for (int b = 0; b < BT; ++b) {
            const float4 av = *(const float4*)&h2_l[b][k4 * 4];  // broadcast
            a3[b] += w3r[4*k4+0] * av.x + w3r[4*k4+1] * av.y
                   + w3r[4*k4+2] * av.z + w3r[4*k4+3] * av.w;
          }
        }
        // streamed half: k = 64..127, octet-cooperative
        float4 h2a[BT], h2b[BT];
        #pragma unroll
        for (int b = 0; b < BT; ++b) {
          h2a[b] = *(const float4*)&h2_l[b][64 + 4 * d];
          h2b[b] = *(const float4*)&h2_l[b][96 + 4 * d];
        }
        const float* vw3s = vw3;
        asm volatile("" : "+v"(vw3s));     // opaque: forbid hoisting the stream
        #pragma unroll 2
        for (int rr = 0; rr < 8; ++rr) {
          const float* rowp = vw3s + (h3 * 8 + rr) * Wn + 64 + d * 4;
          const float4 v1 = *(const float4*)(rowp);
          const float4 v2 = *(const float4*)(rowp + 32);
          #pragma unroll
          for (int b = 0; b < BT; ++b) {
            float pp = dot4(v1, h2a[b]) + dot4(v2, h2b[b]);
            pp += __shfl_xor(pp, 1, 64);
            pp += __shfl_xor(pp, 2, 64);
            pp += __shfl_xor(pp, 4, 64);
            if (rr == d) a3[b] += pp;      // my row's streamed dot
          }
        }
        float kv = 0.f;
        #pragma unroll
        for (int b = 0; b < BT; ++b) {
          float p = tanhf(a3[b] + b3r) * dxr[b];
          p += __shfl_xor(p, 1, 64);        // reduce over d (lane bits 0-2)
          p += __shfl_xor(p, 2, 64);
          p += __shfl_xor(p, 4, 64);
          if (d == b) kv = p;
        }
        if (d < BT) K_l[s][d][h3] = kv;
      }
      __syncthreads();
      // ---- stage prep / final update ----
      if (tid < BT * Hn) {
        const int b = tid >> 6, h = tid & (Hn - 1);
        float v = y_l[b][h];
        if (s == 0)      v += A21 * K_l[0][b][h];
        else if (s == 1) v += A31 * K_l[0][b][h] + A32 * K_l[1][b][h];
        else if (s == 2) v += A41 * K_l[0][b][h] + A42 * K_l[1][b][h] + A43 * K_l[2][b][h];
        else if (s == 3) v += A51 * K_l[0][b][h] + A52 * K_l[1][b][h] + A53 * K_l[2][b][h] + A54 * K_l[3][b][h];
        else if (s == 4) v += A61 * K_l[0][b][h] + A62 * K_l[1][b][h] + A63 * K_l[2][b][h] + A64 * K_l[3][b][h] + A65 * K_l[4][b][h];
        else             v += Bc1 * K_l[0][b][h] + Bc2 * K_l[1][b][h] + Bc3 * K_l[2][b][h]
                            + Bc4 * K_l[3][b][h] + Bc5 * K_l[4][b][h] + Bc6 * K_l[5][b][h];
        if (s < 5) ys_l[b][h] = v; else y_l[b][h] = v;
      }
      __syncthreads();
    }
    readout(t + 1);
  }
}

extern "C" void kernel_launch(void* const* d_in, const int* in_sizes, int n_in,
                              void* d_out, int out_size, void* d_ws, size_t ws_size,
                              hipStream_t stream) {
  const float* xs  = (const float*)d_in[1];
  const float* iw1 = (const float*)d_in[2];
  const float* ib1 = (const float*)d_in[3];
  const float* iw2 = (const float*)d_in[4];
  const float* ib2 = (const float*)d_in[5];
  const float* iw3 = (const float*)d_in[6];
  const float* ib3 = (const float*)d_in[7];
  const float* vw1 = (const float*)d_in[8];
  const float* vb1 = (const float*)d_in[9];
  const float* vw2 = (const float*)d_in[10];
  const float* vb2 = (const float*)d_in[11];
  const float* vw3 = (const float*)d_in[12];
  const float* vb3 = (const float*)d_in[13];
  const float* lw  = (const float*)d_in[14];
  const float* lb  = (const float*)d_in[15];
  float* out = (float*)d_out;

  ncde_kernel<<<Bb / BT, NT, 0, stream>>>(xs, iw1, ib1, iw2, ib2, iw3, ib3,
                                          vw1, vb1, vw2, vb2, vw3, vb3, lw, lb, out);
}

// Round 4
// 3465.325 us; speedup vs baseline: 6.7142x; 1.2147x over previous
//
#include <hip/hip_runtime.h>
#include <math.h>

namespace {

constexpr int Bb = 1024;
constexpr int Tn = 64;
constexpr int Dn = 8;
constexpr int Hn = 64;
constexpr int Wn = 128;
constexpr int BT = 4;    // batch rows per block
constexpr int NT = 512;  // threads per block
constexpr int W1S = 68;  // w1s row stride: 68 % 32 == 4 -> 2-way max (free)
constexpr int W2S = 132; // w2s row stride: 132 % 32 == 4 -> 2-way max (free)

// Tsit5 tableau
constexpr float A21 = 0.161f;
constexpr float A31 = -0.008480655492356989f, A32 = 0.335480655492357f;
constexpr float A41 = 2.8971530571054935f, A42 = -6.359448489975075f, A43 = 4.3622954328695815f;
constexpr float A51 = 5.325864828439257f, A52 = -11.748883564062828f, A53 = 7.4955393428898365f, A54 = -0.09249506636175525f;
constexpr float A61 = 5.86145544294642f, A62 = -12.92096931784711f, A63 = 8.159367898576159f, A64 = -0.071584973281401f, A65 = -0.028269050394068383f;
constexpr float Bc1 = 0.09646076681806523f, Bc2 = 0.01f, Bc3 = 0.4798896504144996f;
constexpr float Bc4 = 1.379008574103742f, Bc5 = -3.290069515436081f, Bc6 = 2.324710524099774f;

// fast transcendentals (v_exp/v_log/v_rcp based; ~1e-7 rel err, vs ~40+ slot libm)
__device__ inline float fast_softplus(float x) {
  const float e = __expf(-fabsf(x));           // e in (0,1]: no overflow
  return fmaxf(x, 0.f) + __logf(1.f + e);      // 1+e in [1,2]: well-conditioned
}
__device__ inline float fast_tanh(float x) {
  const float xc = fminf(fmaxf(x, -10.f), 10.f);  // tanh(+-10)==+-1 in fp32
  const float e2 = __expf(2.f * xc);
  return 1.f - __fdividef(2.f, e2 + 1.f);
}
__device__ inline float fast_sigmoid(float z) {
  return __fdividef(1.f, 1.f + __expf(-z));
}
__device__ inline float dot4(float4 w, float4 a) {
  return w.x * a.x + w.y * a.y + w.z * a.z + w.w * a.w;
}

} // namespace

// Persistent per-batch-tile NeuralCDE integrator, 512 threads/block.
//
// R3 killed the spill (FETCH 41GB->4MB); R4 attacks instruction-issue count:
//  * L1/L2: no k-split. Thread (b=tid&3, o=tid>>2) computes the FULL dot.
//    w1/w2 row-major in LDS (stride 68/132 -> 2-way/free), read as float4.
//    Removes 16 swizzles + selects/stage and all scalar ds_reads.
//  * L3: thread tid owns row tid. Front 64 k in regs (w3r[64]); back 64 k
//    streamed per-lane from global (L2-hot, 256KB shared per XCD) in 16-reg
//    chunks, software-pipelined: chunk0 issued BEFORE L1 so latency hides
//    under L1+L2. No octet sharing -> 96 swizzles + 32 selects/stage gone.
//  * libm softplus/tanhf/sigmoid -> __expf/__logf/__fdividef forms.
// Peak VGPR ~116 < 128 cap (1024/8waves budget): no spill by design.
__global__ __attribute__((amdgpu_waves_per_eu(2, 2))) __launch_bounds__(NT)
void ncde_kernel(const float* __restrict__ xs,
                 const float* __restrict__ iw1, const float* __restrict__ ib1,
                 const float* __restrict__ iw2, const float* __restrict__ ib2,
                 const float* __restrict__ iw3, const float* __restrict__ ib3,
                 const float* __restrict__ vw1, const float* __restrict__ vb1,
                 const float* __restrict__ vw2, const float* __restrict__ vb2,
                 const float* __restrict__ vw3, const float* __restrict__ vb3,
                 const float* __restrict__ lw,  const float* __restrict__ lb,
                 float* __restrict__ out)
{
  __shared__ float w1s[Wn][W1S];          // 34.8 KB: w1s[o][k] row-major
  __shared__ float w2s[Wn][W2S];          // 67.6 KB: w2s[o][k] row-major
  __shared__ float xs_l[BT][Tn * Dn];     // 8 KB control path
  __shared__ float y_l[BT][Hn];           // current state
  __shared__ float ys_l[BT][Hn];          // stage input
  __shared__ float K_l[6][BT][Hn];        // dt-scaled stage slopes
  __shared__ float h1_l[BT][Wn];
  __shared__ float h2_l[BT][Wn];
  __shared__ float dxs_l[BT][Dn];         // xs[t+1]-xs[t] (== dt * dX/dt)
  __shared__ float lw_l[Hn];

  const int tid = threadIdx.x;
  const int b12 = tid & 3;        // L1/L2 batch row
  const int o   = tid >> 2;       // L1/L2 output neuron, 0..127
  const int d   = tid & 7;        // L3 data-dim (row tid = h3*8+d)
  const int h3  = tid >> 3;       // L3 hidden index, 0..63
  const int b0  = blockIdx.x * BT;

  // ---- vw3 row tid, FRONT half (k=0..63) -> registers (one-time) ----
  float w3r[64];
  {
    const float4* p = (const float4*)(vw3 + tid * Wn);
    #pragma unroll
    for (int i = 0; i < 16; ++i) {
      float4 v = p[i];
      w3r[4*i+0] = v.x; w3r[4*i+1] = v.y; w3r[4*i+2] = v.z; w3r[4*i+3] = v.w;
    }
  }
  const float b1r = vb1[o];
  const float b2r = vb2[o];
  const float b3r = vb3[tid];
  const float lb0 = lb[0];

  // ---- stage w1/w2 row-major into LDS (wave writes one row: conflict-free) ----
  #pragma unroll
  for (int i = 0; i < 16; ++i) {          // 8192 f32 / 512 threads
    const int e = i * NT + tid;           // e = o*64 + k
    w1s[e >> 6][e & 63] = vw1[e];
  }
  #pragma unroll
  for (int i = 0; i < 32; ++i) {          // 16384 f32 / 512 threads
    const int e = i * NT + tid;           // e = o*128 + k
    w2s[e >> 7][e & 127] = vw2[e];
  }
  // ---- this block's xs rows (512 x float4 = 8 KB) ----
  ((float4*)&xs_l[0][0])[tid] = ((const float4*)(xs + b0 * Tn * Dn))[tid];
  if (tid < Hn) lw_l[tid] = lw[tid];
  __syncthreads();

  // ---- initial MLP (relu, relu, identity): y0 = mlp(xs[:,0]) ----
  {
    float acc = ib1[o];
    #pragma unroll
    for (int k = 0; k < Dn; ++k) acc += iw1[o * Dn + k] * xs_l[b12][k];
    h1_l[b12][o] = fmaxf(acc, 0.f);
  }
  __syncthreads();
  {
    float acc = ib2[o];
    const float4* wrow = (const float4*)(iw2 + o * Wn);
    #pragma unroll
    for (int k4 = 0; k4 < Wn / 4; ++k4)
      acc += dot4(wrow[k4], *(const float4*)&h1_l[b12][k4 * 4]);
    h2_l[b12][o] = fmaxf(acc, 0.f);
  }
  __syncthreads();
  if (tid < BT * Hn) {
    const int b = tid >> 6, h = tid & (Hn - 1);
    float acc = ib3[h];
    const float4* wrow = (const float4*)(iw3 + h * Wn);
    #pragma unroll
    for (int k4 = 0; k4 < Wn / 4; ++k4)
      acc += dot4(wrow[k4], *(const float4*)&h2_l[b][k4 * 4]);
    y_l[b][h] = acc;
  }
  __syncthreads();

  auto readout = [&](int t) {
    if (tid < BT * Hn) {
      const int wv = tid >> 6, h = tid & (Hn - 1);
      float p = lw_l[h] * y_l[wv][h];
      #pragma unroll
      for (int off = 32; off > 0; off >>= 1) p += __shfl_xor(p, off, 64);
      if (h == 0) out[(b0 + wv) * Tn + t] = fast_sigmoid(p + lb0);
    }
  };
  readout(0);

  const float* vp_base = vw3 + tid * Wn + 64;   // my row's back half

  // ---- 63 Tsit5 steps ----
  #pragma unroll 1
  for (int t = 0; t < Tn - 1; ++t) {
    if (tid < BT * Hn) {
      const int b = tid >> 6, h = tid & (Hn - 1);
      ys_l[b][h] = y_l[b][h];               // stage-1 input is y
    } else if (tid < BT * Hn + BT * Dn) {
      const int r = tid - BT * Hn;
      const int b = r >> 3, dd = r & 7;
      dxs_l[b][dd] = xs_l[b][(t + 1) * Dn + dd] - xs_l[b][t * Dn + dd];
    }
    __syncthreads();

    float dxr[BT];
    #pragma unroll
    for (int b = 0; b < BT; ++b) dxr[b] = dxs_l[b][d];

    #pragma unroll 1
    for (int s = 0; s < 6; ++s) {
      // streamed w3 back half: opaque base per stage (no LICM -> no spill),
      // chunk A issued EARLY so L2 latency hides under L1+L2 compute.
      const float* vp = vp_base;
      asm volatile("" : "+v"(vp));
      const float4* vp4 = (const float4*)vp;
      float4 wsA[4], wsB[4];
      #pragma unroll
      for (int j = 0; j < 4; ++j) wsA[j] = vp4[j];         // k 64..79

      // ---- vf layer 1: thread (b12,o) full 64-k dot ----
      {
        float acc = b1r;
        #pragma unroll
        for (int k4 = 0; k4 < 16; ++k4)
          acc += dot4(*(const float4*)&w1s[o][k4 * 4],
                      *(const float4*)&ys_l[b12][k4 * 4]);
        h1_l[b12][o] = fast_softplus(acc);
      }
      __syncthreads();
      // ---- vf layer 2: thread (b12,o) full 128-k dot ----
      {
        float acc = b2r;
        #pragma unroll
        for (int k4 = 0; k4 < 32; ++k4)
          acc += dot4(*(const float4*)&w2s[o][k4 * 4],
                      *(const float4*)&h1_l[b12][k4 * 4]);
        h2_l[b12][o] = fast_softplus(acc);
      }
      __syncthreads();
      // ---- vf layer 3: row tid, front half regs + back half streamed ----
      {
        #pragma unroll
        for (int j = 0; j < 4; ++j) wsB[j] = vp4[4 + j];   // k 80..95
        float a3[BT] = {0.f, 0.f, 0.f, 0.f};
        // register half: k = 0..63 (uniform broadcast h2 reads)
        #pragma unroll
        for (int k4 = 0; k4 < 16; ++k4) {
          #pragma unroll
          for (int b = 0; b < BT; ++b) {
            const float4 av = *(const float4*)&h2_l[b][k4 * 4];
            a3[b] += w3r[4*k4+0] * av.x + w3r[4*k4+1] * av.y
                   + w3r[4*k4+2] * av.z + w3r[4*k4+3] * av.w;
          }
        }
        // chunk A: k 64..79, then refill A with k 96..111
        #pragma unroll
        for (int j = 0; j < 4; ++j)
          #pragma unroll
          for (int b = 0; b < BT; ++b)
            a3[b] += dot4(wsA[j], *(const float4*)&h2_l[b][64 + j * 4]);
        #pragma unroll
        for (int j = 0; j < 4; ++j) wsA[j] = vp4[8 + j];   // k 96..111
        // chunk B: k 80..95, then refill B with k 112..127
        #pragma unroll
        for (int j = 0; j < 4; ++j)
          #pragma unroll
          for (int b = 0; b < BT; ++b)
            a3[b] += dot4(wsB[j], *(const float4*)&h2_l[b][80 + j * 4]);
        #pragma unroll
        for (int j = 0; j < 4; ++j) wsB[j] = vp4[12 + j];  // k 112..127
        #pragma unroll
        for (int j = 0; j < 4; ++j)
          #pragma unroll
          for (int b = 0; b < BT; ++b)
            a3[b] += dot4(wsA[j], *(const float4*)&h2_l[b][96 + j * 4]);
        #pragma unroll
        for (int j = 0; j < 4; ++j)
          #pragma unroll
          for (int b = 0; b < BT; ++b)
            a3[b] += dot4(wsB[j], *(const float4*)&h2_l[b][112 + j * 4]);

        // tanh + einsum over d (octet reduce, 3 swizzles per b)
        float kv = 0.f;
        #pragma unroll
        for (int b = 0; b < BT; ++b) {
          float p = fast_tanh(a3[b] + b3r) * dxr[b];
          p += __shfl_xor(p, 1, 64);
          p += __shfl_xor(p, 2, 64);
          p += __shfl_xor(p, 4, 64);
          if (d == b) kv = p;
        }
        if (d < BT) K_l[s][d][h3] = kv;
      }
      __syncthreads();
      // ---- stage prep / final update ----
      if (tid < BT * Hn) {
        const int b = tid >> 6, h = tid & (Hn - 1);
        float v = y_l[b][h];
        if (s == 0)      v += A21 * K_l[0][b][h];
        else if (s == 1) v += A31 * K_l[0][b][h] + A32 * K_l[1][b][h];
        else if (s == 2) v += A41 * K_l[0][b][h] + A42 * K_l[1][b][h] + A43 * K_l[2][b][h];
        else if (s == 3) v += A51 * K_l[0][b][h] + A52 * K_l[1][b][h] + A53 * K_l[2][b][h] + A54 * K_l[3][b][h];
        else if (s == 4) v += A61 * K_l[0][b][h] + A62 * K_l[1][b][h] + A63 * K_l[2][b][h] + A64 * K_l[3][b][h] + A65 * K_l[4][b][h];
        else             v += Bc1 * K_l[0][b][h] + Bc2 * K_l[1][b][h] + Bc3 * K_l[2][b][h]
                            + Bc4 * K_l[3][b][h] + Bc5 * K_l[4][b][h] + Bc6 * K_l[5][b][h];
        if (s < 5) ys_l[b][h] = v; else y_l[b][h] = v;
      }
      __syncthreads();
    }
    readout(t + 1);
  }
}

extern "C" void kernel_launch(void* const* d_in, const int* in_sizes, int n_in,
                              void* d_out, int out_size, void* d_ws, size_t ws_size,
                              hipStream_t stream) {
  const float* xs  = (const float*)d_in[1];
  const float* iw1 = (const float*)d_in[2];
  const float* ib1 = (const float*)d_in[3];
  const float* iw2 = (const float*)d_in[4];
  const float* ib2 = (const float*)d_in[5];
  const float* iw3 = (const float*)d_in[6];
  const float* ib3 = (const float*)d_in[7];
  const float* vw1 = (const float*)d_in[8];
  const float* vb1 = (const float*)d_in[9];
  const float* vw2 = (const float*)d_in[10];
  const float* vb2 = (const float*)d_in[11];
  const float* vw3 = (const float*)d_in[12];
  const float* vb3 = (const float*)d_in[13];
  const float* lw  = (const float*)d_in[14];
  const float* lb  = (const float*)d_in[15];
  float* out = (float*)d_out;

  ncde_kernel<<<Bb / BT, NT, 0, stream>>>(xs, iw1, ib1, iw2, ib2, iw3, ib3,
                                          vw1, vb1, vw2, vb2, vw3, vb3, lw, lb, out);
}

// Round 5
// 2968.276 us; speedup vs baseline: 7.8385x; 1.1675x over previous
//
#include <hip/hip_runtime.h>
#include <math.h>

namespace {

constexpr int Bb = 1024;
constexpr int Tn = 64;
constexpr int Dn = 8;
constexpr int Hn = 64;
constexpr int Wn = 128;
constexpr int BT = 4;    // batch rows per block
constexpr int NT = 512;  // threads per block
constexpr int W1S = 68;  // w1s row stride: rows 4 banks apart -> 2-way max (free)
constexpr int W2S = 132; // w2s row stride: same property
constexpr int YS  = 72;  // y/ys row stride: rows 8 banks apart, 288B (16B-aligned)
                         // -> 4 batch rows on quads {0,2,4,6}: conflict-free b128
constexpr int HS  = 136; // h1/h2 row stride: 544B, same property
constexpr int KS  = 68;  // K_l inner stride: scalar reads, d*68%32={0,4,8,12}: free

// Tsit5 tableau
constexpr float A21 = 0.161f;
constexpr float A31 = -0.008480655492356989f, A32 = 0.335480655492357f;
constexpr float A41 = 2.8971530571054935f, A42 = -6.359448489975075f, A43 = 4.3622954328695815f;
constexpr float A51 = 5.325864828439257f, A52 = -11.748883564062828f, A53 = 7.4955393428898365f, A54 = -0.09249506636175525f;
constexpr float A61 = 5.86145544294642f, A62 = -12.92096931784711f, A63 = 8.159367898576159f, A64 = -0.071584973281401f, A65 = -0.028269050394068383f;
constexpr float Bc1 = 0.09646076681806523f, Bc2 = 0.01f, Bc3 = 0.4798896504144996f;
constexpr float Bc4 = 1.379008574103742f, Bc5 = -3.290069515436081f, Bc6 = 2.324710524099774f;

// fast transcendentals (v_exp/v_log/v_rcp based)
__device__ inline float fast_softplus(float x) {
  const float e = __expf(-fabsf(x));           // e in (0,1]
  return fmaxf(x, 0.f) + __logf(1.f + e);      // 1+e in [1,2]
}
__device__ inline float fast_tanh(float x) {
  const float xc = fminf(fmaxf(x, -10.f), 10.f);
  const float e2 = __expf(2.f * xc);
  return 1.f - __fdividef(2.f, e2 + 1.f);
}
__device__ inline float fast_sigmoid(float z) {
  return __fdividef(1.f, 1.f + __expf(-z));
}
__device__ inline float dot4(float4 w, float4 a) {
  return w.x * a.x + w.y * a.y + w.z * a.z + w.w * a.w;
}

} // namespace

// Persistent per-batch-tile NeuralCDE integrator, 512 threads/block.
//
// R5 vs R4 (3465us, VALUBusy 40%, 4.6e8 bank-conflict cycles ~= 0.75ms):
//  1. CONFLICT FIX: activation rows were 64/128 floats apart (= 0 mod 32
//     banks) -> every b12-quad ds_read_b128 was a 4-way conflict. Row
//     strides padded to 72/136 (rows on bank-quads {0,2,4,6}: free).
//  2. BARRIER/PASS FUSION: after the octet shfl-reduce every lane holds all
//     4 batch K-totals, so lane d<4 writes K_l[s][d][h3] AND applies the
//     tableau update to ys_l/y_l right there (own-h3 data only -> no extra
//     barrier). Prep pass gone too: dxr computed in-register at s==0 from
//     broadcast xs_l reads; s=5 writes both y_l and ys_l. 26 -> 18
//     barriers/step, two half-idle passes removed.
// VGPR budget unchanged by design: w3r 64 + wsA/wsB 32 + ~25 transients.
__global__ __attribute__((amdgpu_waves_per_eu(2, 2))) __launch_bounds__(NT)
void ncde_kernel(const float* __restrict__ xs,
                 const float* __restrict__ iw1, const float* __restrict__ ib1,
                 const float* __restrict__ iw2, const float* __restrict__ ib2,
                 const float* __restrict__ iw3, const float* __restrict__ ib3,
                 const float* __restrict__ vw1, const float* __restrict__ vb1,
                 const float* __restrict__ vw2, const float* __restrict__ vb2,
                 const float* __restrict__ vw3, const float* __restrict__ vb3,
                 const float* __restrict__ lw,  const float* __restrict__ lb,
                 float* __restrict__ out)
{
  __shared__ float w1s[Wn][W1S];          // 34.8 KB: w1s[o][k] row-major
  __shared__ float w2s[Wn][W2S];          // 67.6 KB: w2s[o][k] row-major
  __shared__ float xs_l[BT][Tn * Dn];     // 8 KB control path
  __shared__ float y_l[BT][YS];           // current state (padded rows)
  __shared__ float ys_l[BT][YS];          // stage input  (padded rows)
  __shared__ float K_l[6][BT][KS];        // stage slopes (padded inner)
  __shared__ float h1_l[BT][HS];
  __shared__ float h2_l[BT][HS];
  __shared__ float lw_l[Hn];

  const int tid = threadIdx.x;
  const int b12 = tid & 3;        // L1/L2 batch row
  const int o   = tid >> 2;       // L1/L2 output neuron, 0..127
  const int d   = tid & 7;        // L3 data-dim (row tid = h3*8+d)
  const int h3  = tid >> 3;       // L3 hidden index, 0..63
  const int b0  = blockIdx.x * BT;

  // ---- vw3 row tid, FRONT half (k=0..63) -> registers (one-time) ----
  float w3r[64];
  {
    const float4* p = (const float4*)(vw3 + tid * Wn);
    #pragma unroll
    for (int i = 0; i < 16; ++i) {
      float4 v = p[i];
      w3r[4*i+0] = v.x; w3r[4*i+1] = v.y; w3r[4*i+2] = v.z; w3r[4*i+3] = v.w;
    }
  }
  const float b1r = vb1[o];
  const float b2r = vb2[o];
  const float b3r = vb3[tid];
  const float lb0 = lb[0];

  // ---- stage w1/w2 row-major into LDS ----
  #pragma unroll
  for (int i = 0; i < 16; ++i) {          // 8192 f32 / 512 threads
    const int e = i * NT + tid;           // e = o*64 + k
    w1s[e >> 6][e & 63] = vw1[e];
  }
  #pragma unroll
  for (int i = 0; i < 32; ++i) {          // 16384 f32 / 512 threads
    const int e = i * NT + tid;           // e = o*128 + k
    w2s[e >> 7][e & 127] = vw2[e];
  }
  // ---- this block's xs rows (512 x float4 = 8 KB) ----
  ((float4*)&xs_l[0][0])[tid] = ((const float4*)(xs + b0 * Tn * Dn))[tid];
  if (tid < Hn) lw_l[tid] = lw[tid];
  __syncthreads();

  // ---- initial MLP (relu, relu, identity): y0 = mlp(xs[:,0]) ----
  {
    float acc = ib1[o];
    #pragma unroll
    for (int k = 0; k < Dn; ++k) acc += iw1[o * Dn + k] * xs_l[b12][k];
    h1_l[b12][o] = fmaxf(acc, 0.f);
  }
  __syncthreads();
  {
    float acc = ib2[o];
    const float4* wrow = (const float4*)(iw2 + o * Wn);
    #pragma unroll
    for (int k4 = 0; k4 < Wn / 4; ++k4)
      acc += dot4(wrow[k4], *(const float4*)&h1_l[b12][k4 * 4]);
    h2_l[b12][o] = fmaxf(acc, 0.f);
  }
  __syncthreads();
  if (tid < BT * Hn) {
    const int b = tid >> 6, h = tid & (Hn - 1);
    float acc = ib3[h];
    const float4* wrow = (const float4*)(iw3 + h * Wn);
    #pragma unroll
    for (int k4 = 0; k4 < Wn / 4; ++k4)
      acc += dot4(wrow[k4], *(const float4*)&h2_l[b][k4 * 4]);
    y_l[b][h]  = acc;
    ys_l[b][h] = acc;                     // stage-1 input for t=0
  }
  __syncthreads();

  auto readout = [&](int t) {
    if (tid < BT * Hn) {
      const int wv = tid >> 6, h = tid & (Hn - 1);
      float p = lw_l[h] * y_l[wv][h];
      #pragma unroll
      for (int off = 32; off > 0; off >>= 1) p += __shfl_xor(p, off, 64);
      if (h == 0) out[(b0 + wv) * Tn + t] = fast_sigmoid(p + lb0);
    }
  };
  readout(0);

  const float* vp_base = vw3 + tid * Wn + 64;   // my row's back half

  // ---- 63 Tsit5 steps; per stage: L1 -> bar -> L2 -> bar -> L3+update -> bar
  #pragma unroll 1
  for (int t = 0; t < Tn - 1; ++t) {
    float dxr[BT];                        // filled at s==0 from xs_l

    #pragma unroll 1
    for (int s = 0; s < 6; ++s) {
      // streamed w3 back half: opaque base per stage (no LICM -> no spill),
      // chunk A issued EARLY so L2 latency hides under L1+L2 compute.
      const float* vp = vp_base;
      asm volatile("" : "+v"(vp));
      const float4* vp4 = (const float4*)vp;
      float4 wsA[4], wsB[4];
      #pragma unroll
      for (int j = 0; j < 4; ++j) wsA[j] = vp4[j];         // k 64..79

      if (s == 0) {
        #pragma unroll
        for (int b = 0; b < BT; ++b)      // broadcast reads, conflict-free
          dxr[b] = xs_l[b][(t + 1) * Dn + d] - xs_l[b][t * Dn + d];
      }

      // ---- vf layer 1: thread (b12,o) full 64-k dot ----
      {
        float acc = b1r;
        #pragma unroll
        for (int k4 = 0; k4 < 16; ++k4)
          acc += dot4(*(const float4*)&w1s[o][k4 * 4],
                      *(const float4*)&ys_l[b12][k4 * 4]);
        h1_l[b12][o] = fast_softplus(acc);
      }
      __syncthreads();
      // ---- vf layer 2: thread (b12,o) full 128-k dot ----
      {
        float acc = b2r;
        #pragma unroll
        for (int k4 = 0; k4 < 32; ++k4)
          acc += dot4(*(const float4*)&w2s[o][k4 * 4],
                      *(const float4*)&h1_l[b12][k4 * 4]);
        h2_l[b12][o] = fast_softplus(acc);
      }
      __syncthreads();
      // ---- vf layer 3 + fused tableau update ----
      {
        #pragma unroll
        for (int j = 0; j < 4; ++j) wsB[j] = vp4[4 + j];   // k 80..95
        float a3[BT] = {0.f, 0.f, 0.f, 0.f};
        // register half: k = 0..63 (uniform broadcast h2 reads)
        #pragma unroll
        for (int k4 = 0; k4 < 16; ++k4) {
          #pragma unroll
          for (int b = 0; b < BT; ++b) {
            const float4 av = *(const float4*)&h2_l[b][k4 * 4];
            a3[b] += w3r[4*k4+0] * av.x + w3r[4*k4+1] * av.y
                   + w3r[4*k4+2] * av.z + w3r[4*k4+3] * av.w;
          }
        }
        // chunk A: k 64..79, then refill A with k 96..111
        #pragma unroll
        for (int j = 0; j < 4; ++j)
          #pragma unroll
          for (int b = 0; b < BT; ++b)
            a3[b] += dot4(wsA[j], *(const float4*)&h2_l[b][64 + j * 4]);
        #pragma unroll
        for (int j = 0; j < 4; ++j) wsA[j] = vp4[8 + j];   // k 96..111
        // chunk B: k 80..95, then refill B with k 112..127
        #pragma unroll
        for (int j = 0; j < 4; ++j)
          #pragma unroll
          for (int b = 0; b < BT; ++b)
            a3[b] += dot4(wsB[j], *(const float4*)&h2_l[b][80 + j * 4]);
        #pragma unroll
        for (int j = 0; j < 4; ++j) wsB[j] = vp4[12 + j];  // k 112..127
        #pragma unroll
        for (int j = 0; j < 4; ++j)
          #pragma unroll
          for (int b = 0; b < BT; ++b)
            a3[b] += dot4(wsA[j], *(const float4*)&h2_l[b][96 + j * 4]);
        #pragma unroll
        for (int j = 0; j < 4; ++j)
          #pragma unroll
          for (int b = 0; b < BT; ++b)
            a3[b] += dot4(wsB[j], *(const float4*)&h2_l[b][112 + j * 4]);

        // tanh + einsum over d: after the 3-shfl reduce the whole octet has
        // each batch total; lane d<4 keeps batch d's.
        float kv = 0.f;
        #pragma unroll
        for (int b = 0; b < BT; ++b) {
          float p = fast_tanh(a3[b] + b3r) * dxr[b];
          p += __shfl_xor(p, 1, 64);
          p += __shfl_xor(p, 2, 64);
          p += __shfl_xor(p, 4, 64);
          if (d == b) kv = p;
        }
        // fused update: own-h3 data only, no barrier needed before it
        if (d < BT) {
          K_l[s][d][h3] = kv;
          float v = y_l[d][h3];
          if (s == 0)      v += A21 * kv;
          else if (s == 1) v += A31 * K_l[0][d][h3] + A32 * kv;
          else if (s == 2) v += A41 * K_l[0][d][h3] + A42 * K_l[1][d][h3] + A43 * kv;
          else if (s == 3) v += A51 * K_l[0][d][h3] + A52 * K_l[1][d][h3]
                              + A53 * K_l[2][d][h3] + A54 * kv;
          else if (s == 4) v += A61 * K_l[0][d][h3] + A62 * K_l[1][d][h3]
                              + A63 * K_l[2][d][h3] + A64 * K_l[3][d][h3] + A65 * kv;
          else             v += Bc1 * K_l[0][d][h3] + Bc2 * K_l[1][d][h3]
                              + Bc3 * K_l[2][d][h3] + Bc4 * K_l[3][d][h3]
                              + Bc5 * K_l[4][d][h3] + Bc6 * kv;
          if (s < 5) {
            ys_l[d][h3] = v;
          } else {
            y_l[d][h3]  = v;
            ys_l[d][h3] = v;              // next step's stage-1 input
          }
        }
      }
      __syncthreads();
    }
    readout(t + 1);
  }
}

extern "C" void kernel_launch(void* const* d_in, const int* in_sizes, int n_in,
                              void* d_out, int out_size, void* d_ws, size_t ws_size,
                              hipStream_t stream) {
  const float* xs  = (const float*)d_in[1];
  const float* iw1 = (const float*)d_in[2];
  const float* ib1 = (const float*)d_in[3];
  const float* iw2 = (const float*)d_in[4];
  const float* ib2 = (const float*)d_in[5];
  const float* iw3 = (const float*)d_in[6];
  const float* ib3 = (const float*)d_in[7];
  const float* vw1 = (const float*)d_in[8];
  const float* vb1 = (const float*)d_in[9];
  const float* vw2 = (const float*)d_in[10];
  const float* vb2 = (const float*)d_in[11];
  const float* vw3 = (const float*)d_in[12];
  const float* vb3 = (const float*)d_in[13];
  const float* lw  = (const float*)d_in[14];
  const float* lb  = (const float*)d_in[15];
  float* out = (float*)d_out;

  ncde_kernel<<<Bb / BT, NT, 0, stream>>>(xs, iw1, ib1, iw2, ib2, iw3, ib3,
                                          vw1, vb1, vw2, vb2, vw3, vb3, lw, lb, out);
}